// Round 5
// baseline (476.740 us; speedup 1.0000x reference)
//
#include <hip/hip_runtime.h>
#include <math.h>

#define DIMC 1024
#define SEQ 4096
#define BATCH 4
#define NH 16
#define HD 64
#define MTOT (BATCH * SEQ)      // 16384 rows
#define NSPLIT 8
#define PELEMS (64 * 64 * 64 + 64 * 64)   // KV partial + Z partial per split
#define EPS 1e-6f

typedef __bf16 bf16x8 __attribute__((ext_vector_type(8)));
typedef __bf16 bf16x4 __attribute__((ext_vector_type(4)));
typedef __bf16 bf16x2 __attribute__((ext_vector_type(2)));
typedef float  f32x4  __attribute__((ext_vector_type(4)));

__device__ __forceinline__ float phi_f(float x) {
    return x > 0.0f ? x + 1.0f : __expf(x);   // elu(x)+1
}

// ---------------------------------------------------------------------------
// One-shot fp32->bf16 conversion of x + all 4 weight matrices.
// ---------------------------------------------------------------------------
__global__ __launch_bounds__(256) void cvt_all(
    const float* __restrict__ x,
    const float* __restrict__ Wq, const float* __restrict__ Wk,
    const float* __restrict__ Wv, const float* __restrict__ Wo,
    __bf16* __restrict__ xb,
    __bf16* __restrict__ Wqb, __bf16* __restrict__ Wkb,
    __bf16* __restrict__ Wvb, __bf16* __restrict__ Wob)
{
    const size_t big = (size_t)MTOT * DIMC;
    const size_t wsz = (size_t)DIMC * DIMC;
    size_t i = ((size_t)blockIdx.x * 256 + threadIdx.x) * 4;
    const float* src; __bf16* dst; size_t off;
    if (i < big) { src = x; dst = xb; off = i; }
    else {
        size_t j = i - big;
        int w = (int)(j >> 20);            // /wsz (2^20)
        off = j & (wsz - 1);
        switch (w) {
            case 0: src = Wq; dst = Wqb; break;
            case 1: src = Wk; dst = Wkb; break;
            case 2: src = Wv; dst = Wvb; break;
            default: src = Wo; dst = Wob; break;
        }
    }
    float4 v = *(const float4*)(src + off);
    bf16x4 o = { (__bf16)v.x, (__bf16)v.y, (__bf16)v.z, (__bf16)v.w };
    *(bf16x4*)(dst + off) = o;
}

// ---------------------------------------------------------------------------
// Shared 128x128 MFMA GEMM tile body (m97 structure), conflict-free LDS:
// staging lane map (srow=lane&15, scol=(lane>>4)*8) makes each 16-row group
// land chunk-transposed [quad][row] in LDS, so MFMA fragment reads are
// ds_read_b128 at base + group*1KB + lane*16B -- linear, zero bank
// conflicts, immediate-offset addressing.
// ---------------------------------------------------------------------------
template<int OUT_BF16>
__device__ __forceinline__ void gemm_tile(
    const __bf16* __restrict__ X, const __bf16* __restrict__ W,
    const float* __restrict__ bias, void* __restrict__ Yv,
    int m0, int n0, int do_phi)
{
    __shared__ __attribute__((aligned(16))) __bf16 As[128 * 32]; // 8 groups of [4 chunks][16 rows]x16B
    __shared__ __attribute__((aligned(16))) __bf16 Bs[128 * 32];
    const int tid = threadIdx.x;
    const int wave = tid >> 6, lane = tid & 63;
    const int wm = (wave >> 1) * 64, wn = (wave & 1) * 64;
    const int wmg = (wave >> 1) * 4, wng = (wave & 1) * 4;   // 16-row group idx
    const int srow = lane & 15, scol = (lane >> 4) * 8;      // staging lane map

    f32x4 acc[4][4] = {};

    for (int k0 = 0; k0 < DIMC; k0 += 32) {
        __syncthreads();   // previous tile's ds_reads complete
        #pragma unroll
        for (int g = 0; g < 2; ++g) {
            const int r0 = wave * 16 + g * 64;   // one 16-row group per call
            __builtin_amdgcn_global_load_lds(
                (const __attribute__((address_space(1))) void*)
                    (X + (size_t)(m0 + r0 + srow) * DIMC + k0 + scol),
                (__attribute__((address_space(3))) void*)(As + r0 * 32),
                16, 0, 0);
            __builtin_amdgcn_global_load_lds(
                (const __attribute__((address_space(1))) void*)
                    (W + (size_t)(n0 + r0 + srow) * DIMC + k0 + scol),
                (__attribute__((address_space(3))) void*)(Bs + r0 * 32),
                16, 0, 0);
        }
        __syncthreads();   // vmcnt drain: staged data visible

        bf16x8 af[4], bfr[4];
        #pragma unroll
        for (int i = 0; i < 4; ++i)
            af[i] = *(const bf16x8*)(As + (wmg + i) * 512 + lane * 8);
        #pragma unroll
        for (int j = 0; j < 4; ++j)
            bfr[j] = *(const bf16x8*)(Bs + (wng + j) * 512 + lane * 8);
        #pragma unroll
        for (int i = 0; i < 4; ++i)
            #pragma unroll
            for (int j = 0; j < 4; ++j)
                acc[i][j] = __builtin_amdgcn_mfma_f32_16x16x32_bf16(
                    af[i], bfr[j], acc[i][j], 0, 0, 0);
    }

    // epilogue: C/D layout col=lane&15, row=(lane>>4)*4+reg
    const int col_l = lane & 15, quad = lane >> 4;
    #pragma unroll
    for (int j = 0; j < 4; ++j) {
        const int gcol = n0 + wn + j * 16 + col_l;
        const float bb = bias[gcol];
        #pragma unroll
        for (int i = 0; i < 4; ++i) {
            #pragma unroll
            for (int r = 0; r < 4; ++r) {
                const int grow = m0 + wm + i * 16 + quad * 4 + r;
                float v = acc[i][j][r] + bb;
                if (do_phi) v = phi_f(v);
                if (OUT_BF16)
                    ((__bf16*)Yv)[(size_t)grow * DIMC + gcol] = (__bf16)v;
                else
                    ((float*)Yv)[(size_t)grow * DIMC + gcol] = v;
            }
        }
    }
}

// ---------------------------------------------------------------------------
// Fused Q/K/V projection. 3072 blocks, XCD-swizzled: blocks sharing an
// X-panel (24 = 3 matrices x 8 n-blocks) land on ONE XCD's L2.
// ---------------------------------------------------------------------------
__global__ __launch_bounds__(256, 4) void gemm_qkv(
    const __bf16* __restrict__ X,
    const __bf16* __restrict__ Wq, const __bf16* __restrict__ Wk,
    const __bf16* __restrict__ Wv,
    const float* __restrict__ bq, const float* __restrict__ bk,
    const float* __restrict__ bv,
    __bf16* __restrict__ Q, __bf16* __restrict__ K, __bf16* __restrict__ V)
{
    const int l = blockIdx.x;
    const int xcd = l & 7, s = l >> 3;          // s in [0,384)
    const int m_idx = xcd * 16 + (s / 24);      // 16 m-panels per XCD
    const int inner = s % 24;
    const int mat = inner >> 3, nb = inner & 7;
    const __bf16* W = (mat == 0) ? Wq : (mat == 1) ? Wk : Wv;
    const float* bias = (mat == 0) ? bq : (mat == 1) ? bk : bv;
    __bf16* Y = (mat == 0) ? Q : (mat == 1) ? K : V;
    gemm_tile<1>(X, W, bias, Y, m_idx * 128, nb * 128, mat != 2);
}

// ---------------------------------------------------------------------------
// Output projection: out = A @ Wo^T + bo (fp32 out). XCD-swizzled.
// ---------------------------------------------------------------------------
__global__ __launch_bounds__(256, 4) void gemm_out(
    const __bf16* __restrict__ A, const __bf16* __restrict__ Wo,
    const float* __restrict__ bo, float* __restrict__ out)
{
    const int l = blockIdx.x;
    const int xcd = l & 7, s = l >> 3;          // s in [0,128)
    const int m_idx = xcd * 16 + (s >> 3);
    const int nb = s & 7;
    gemm_tile<0>(A, Wo, bo, out, m_idx * 128, nb * 128, 0);
}

// ---------------------------------------------------------------------------
// Per (b,h,split): partial KV[d][e] = sum_n K[n,d]*V[n,e], partial Z[d].
// MFMA over LDS-transposed tiles; partials streamed, no global atomics.
// ---------------------------------------------------------------------------
__global__ __launch_bounds__(256) void kv_z_kernel(
    const __bf16* __restrict__ Kb, const __bf16* __restrict__ Vb,
    float* __restrict__ P)
{
    __shared__ __attribute__((aligned(16))) __bf16 Kt[64 * 36]; // [d][tok]
    __shared__ __attribute__((aligned(16))) __bf16 Vt[64 * 36]; // [e][tok]
    __shared__ float zs[64];
    const int tid = threadIdx.x, wave = tid >> 6, lane = tid & 63;
    const int bh = blockIdx.x, b = bh >> 4, h = bh & 15;
    const int split = blockIdx.y;
    const int n0 = split * (SEQ / NSPLIT);
    const int dg = (tid & 15) * 4;     // 4 consecutive dims per thread
    const int u2 = (tid >> 4) * 2;     // token pair
    const int fr = lane & 15, fk = (lane >> 4) * 8;
    const __bf16* Kp = Kb + ((size_t)b * SEQ + n0) * DIMC + h * HD;
    const __bf16* Vp = Vb + ((size_t)b * SEQ + n0) * DIMC + h * HD;

    if (tid < 64) zs[tid] = 0.0f;
    f32x4 acc[4] = {};
    float zp[4] = {};

    for (int c = 0; c < SEQ / NSPLIT; c += 32) {
        bf16x4 ka = *(const bf16x4*)(Kp + (size_t)(c + u2) * DIMC + dg);
        bf16x4 kb = *(const bf16x4*)(Kp + (size_t)(c + u2 + 1) * DIMC + dg);
        bf16x4 va = *(const bf16x4*)(Vp + (size_t)(c + u2) * DIMC + dg);
        bf16x4 vb = *(const bf16x4*)(Vp + (size_t)(c + u2 + 1) * DIMC + dg);
        __syncthreads();
        #pragma unroll
        for (int q = 0; q < 4; ++q) {
            zp[q] += (float)ka[q] + (float)kb[q];
            *(bf16x2*)(Kt + (dg + q) * 36 + u2) = bf16x2{ka[q], kb[q]};
            *(bf16x2*)(Vt + (dg + q) * 36 + u2) = bf16x2{va[q], vb[q]};
        }
        __syncthreads();

        const __bf16* ar = Kt + (wave * 16 + fr) * 36 + fk;
        bf16x4 alo = *(const bf16x4*)ar, ahi = *(const bf16x4*)(ar + 4);
        bf16x8 af = {alo[0],alo[1],alo[2],alo[3],ahi[0],ahi[1],ahi[2],ahi[3]};
        #pragma unroll
        for (int j = 0; j < 4; ++j) {
            const __bf16* br = Vt + (j * 16 + fr) * 36 + fk;
            bf16x4 blo = *(const bf16x4*)br, bhi = *(const bf16x4*)(br + 4);
            bf16x8 bf = {blo[0],blo[1],blo[2],blo[3],bhi[0],bhi[1],bhi[2],bhi[3]};
            acc[j] = __builtin_amdgcn_mfma_f32_16x16x32_bf16(af, bf, acc[j], 0, 0, 0);
        }
    }

    #pragma unroll
    for (int q = 0; q < 4; ++q) atomicAdd(&zs[dg + q], zp[q]);
    __syncthreads();

    float* KVp = P + (size_t)split * PELEMS + bh * 4096;
    const int col_l = lane & 15, quad = lane >> 4;
    #pragma unroll
    for (int j = 0; j < 4; ++j)
        #pragma unroll
        for (int r = 0; r < 4; ++r)
            KVp[(wave * 16 + quad * 4 + r) * 64 + j * 16 + col_l] = acc[j][r];
    if (tid < 64)
        P[(size_t)split * PELEMS + 64 * 64 * 64 + bh * 64 + tid] = zs[tid];
}

// sum NSPLIT partials -> final KV+Z (contiguous PELEMS floats)
__global__ __launch_bounds__(256) void reduce_partials(
    const float* __restrict__ P, float* __restrict__ F)
{
    const int i = blockIdx.x * 256 + threadIdx.x;
    if (i < PELEMS) {
        float s = 0.0f;
        #pragma unroll
        for (int sp = 0; sp < NSPLIT; ++sp) s += P[(size_t)sp * PELEMS + i];
        F[i] = s;
    }
}

// ---------------------------------------------------------------------------
// Per (b,h, 32-token chunk): out[n,e] = (sum_d Q[n,d]*KV[d,e]) / (Q[n]·Z + eps)
// ---------------------------------------------------------------------------
__global__ __launch_bounds__(256) void attn_apply(
    const __bf16* __restrict__ Qb, const float* __restrict__ KV,
    const float* __restrict__ Z, __bf16* __restrict__ Ab)
{
    __shared__ __align__(16) float KVs[64][64];
    __shared__ __align__(16) float Qs[32][64];
    __shared__ float Zs[64];
    __shared__ float rnorm[32];
    const int tid = threadIdx.x;
    const int bh = blockIdx.y;
    const int b = bh >> 4, h = bh & 15;
    const int n0 = blockIdx.x * 32;

    const float* KVp = KV + (size_t)bh * HD * HD;
    #pragma unroll
    for (int r = 0; r < 4; ++r) {
        const int idx = (r * 256 + tid) * 4;
        *(float4*)&((float*)KVs)[idx] = *(const float4*)(KVp + idx);
    }
    const __bf16* Qp = Qb + ((size_t)(b * SEQ + n0)) * DIMC + h * HD;
    {
        const int tok = tid >> 3, col = (tid & 7) * 8;
        bf16x8 q8 = *(const bf16x8*)(Qp + (size_t)tok * DIMC + col);
        #pragma unroll
        for (int q = 0; q < 8; ++q) Qs[tok][col + q] = (float)q8[q];
    }
    if (tid < 64) Zs[tid] = Z[bh * HD + tid];
    __syncthreads();

    if (tid < 32) {
        float s = 0.0f;
        #pragma unroll
        for (int d = 0; d < 64; ++d) s += Qs[tid][d] * Zs[d];
        rnorm[tid] = 1.0f / (s + EPS);
    }
    __syncthreads();

    const int trow = tid >> 3;
    const int e0 = (tid & 7) * 8;
    float out[8] = {};
    #pragma unroll
    for (int d = 0; d < 64; ++d) {
        const float q = Qs[trow][d];
        #pragma unroll
        for (int j = 0; j < 8; ++j) out[j] = fmaf(q, KVs[d][e0 + j], out[j]);
    }
    const float rn = rnorm[trow];
    __bf16* Op = Ab + ((size_t)(b * SEQ + n0 + trow)) * DIMC + h * HD + e0;
    bf16x8 o;
    #pragma unroll
    for (int j = 0; j < 8; ++j) o[j] = (__bf16)(out[j] * rn);
    *(bf16x8*)Op = o;
}

extern "C" void kernel_launch(void* const* d_in, const int* in_sizes, int n_in,
                              void* d_out, int out_size, void* d_ws, size_t ws_size,
                              hipStream_t stream) {
    const float* x  = (const float*)d_in[0];
    const float* Wq = (const float*)d_in[1];
    const float* bq = (const float*)d_in[2];
    const float* Wk = (const float*)d_in[3];
    const float* bk = (const float*)d_in[4];
    const float* Wv = (const float*)d_in[5];
    const float* bv = (const float*)d_in[6];
    const float* Wo = (const float*)d_in[7];
    const float* bo = (const float*)d_in[8];
    float* out = (float*)d_out;

    const size_t big = (size_t)MTOT * DIMC;     // 16,777,216 elems
    const size_t wsz = (size_t)DIMC * DIMC;     // 1,048,576 elems
    __bf16* wsp = (__bf16*)d_ws;
    __bf16* xb  = wsp;
    __bf16* Wqb = xb + big;
    __bf16* Wkb = Wqb + wsz;
    __bf16* Wvb = Wkb + wsz;
    __bf16* Wob = Wvb + wsz;
    __bf16* Qb  = Wob + wsz;
    __bf16* Kb  = Qb + big;
    __bf16* Vb  = Kb + big;
    __bf16* Ab  = xb;                            // alias: x dead after QKV
    float*  P   = (float*)(Vb + big);            // NSPLIT * PELEMS partials
    float*  F   = P + (size_t)NSPLIT * PELEMS;
    float*  KV  = F;
    float*  Z   = F + 64 * 64 * 64;

    const size_t ntot = big + 4 * wsz;           // 20,971,520 elems
    cvt_all<<<dim3((int)(ntot / 1024)), 256, 0, stream>>>(
        x, Wq, Wk, Wv, Wo, xb, Wqb, Wkb, Wvb, Wob);

    gemm_qkv<<<dim3(3072), 256, 0, stream>>>(
        xb, Wqb, Wkb, Wvb, bq, bk, bv, Qb, Kb, Vb);

    kv_z_kernel<<<dim3(BATCH * NH, NSPLIT), 256, 0, stream>>>(Kb, Vb, P);
    reduce_partials<<<dim3((PELEMS + 255) / 256), 256, 0, stream>>>(P, F);
    attn_apply<<<dim3(SEQ / 32, BATCH * NH), 256, 0, stream>>>(Qb, KV, Z, Ab);

    gemm_out<<<dim3(1024), 256, 0, stream>>>(Ab, Wob, bo, out);
}

// Round 6
// 385.965 us; speedup vs baseline: 1.2352x; 1.2352x over previous
//
#include <hip/hip_runtime.h>
#include <math.h>

#define DIMC 1024
#define SEQ 4096
#define BATCH 4
#define NH 16
#define HD 64
#define MTOT (BATCH * SEQ)      // 16384 rows
#define NSPLIT 8
#define PELEMS (64 * 64 * 64 + 64 * 64)   // KV partial + Z partial per split
#define EPS 1e-6f

typedef __bf16 bf16x8 __attribute__((ext_vector_type(8)));
typedef __bf16 bf16x4 __attribute__((ext_vector_type(4)));
typedef __bf16 bf16x2 __attribute__((ext_vector_type(2)));
typedef float  f32x4  __attribute__((ext_vector_type(4)));

__device__ __forceinline__ float phi_f(float x) {
    return x > 0.0f ? x + 1.0f : __expf(x);   // elu(x)+1
}

// ---------------------------------------------------------------------------
// One-shot fp32->bf16 conversion of x + all 4 weight matrices.
// ---------------------------------------------------------------------------
__global__ __launch_bounds__(256) void cvt_all(
    const float* __restrict__ x,
    const float* __restrict__ Wq, const float* __restrict__ Wk,
    const float* __restrict__ Wv, const float* __restrict__ Wo,
    __bf16* __restrict__ xb,
    __bf16* __restrict__ Wqb, __bf16* __restrict__ Wkb,
    __bf16* __restrict__ Wvb, __bf16* __restrict__ Wob)
{
    const size_t big = (size_t)MTOT * DIMC;
    const size_t wsz = (size_t)DIMC * DIMC;
    size_t i = ((size_t)blockIdx.x * 256 + threadIdx.x) * 4;
    const float* src; __bf16* dst; size_t off;
    if (i < big) { src = x; dst = xb; off = i; }
    else {
        size_t j = i - big;
        int w = (int)(j >> 20);            // /wsz (2^20)
        off = j & (wsz - 1);
        switch (w) {
            case 0: src = Wq; dst = Wqb; break;
            case 1: src = Wk; dst = Wkb; break;
            case 2: src = Wv; dst = Wvb; break;
            default: src = Wo; dst = Wob; break;
        }
    }
    float4 v = *(const float4*)(src + off);
    bf16x4 o = { (__bf16)v.x, (__bf16)v.y, (__bf16)v.z, (__bf16)v.w };
    *(bf16x4*)(dst + off) = o;
}

// ---------------------------------------------------------------------------
// Shared 128x128 MFMA GEMM tile body (m97 structure). R4-proven staging map:
// lane -> (row=lane>>2, col=(lane&3)*8): consecutive 4 lanes cover one 64B
// row segment -> fully coalesced global requests. LDS tiles row-major
// [128][32]; fragment ds_read_b128 carries a 4-way bank alias (measured
// 1.26e7 conflicts in R4) -- accepted: R5 proved fixing it at the cost of
// request amplification is a large net loss.
// ---------------------------------------------------------------------------
template<int OUT_BF16>
__device__ __forceinline__ void gemm_tile(
    const __bf16* __restrict__ X, const __bf16* __restrict__ W,
    const float* __restrict__ bias, void* __restrict__ Yv,
    int m0, int n0, int do_phi)
{
    __shared__ __attribute__((aligned(16))) __bf16 As[128 * 32]; // [m][k]
    __shared__ __attribute__((aligned(16))) __bf16 Bs[128 * 32]; // [n][k]
    const int tid = threadIdx.x;
    const int wave = tid >> 6, lane = tid & 63;
    const int wm = (wave >> 1) * 64, wn = (wave & 1) * 64;
    const int srow = lane >> 2, scol = (lane & 3) * 8;  // staging lane map
    const int fr = lane & 15, fk = (lane >> 4) * 8;     // fragment lane map

    f32x4 acc[4][4] = {};

    for (int k0 = 0; k0 < DIMC; k0 += 32) {
        __syncthreads();   // previous tile's ds_reads complete
        #pragma unroll
        for (int g = 0; g < 2; ++g) {
            const int r0 = wave * 16 + g * 64;   // one 16-row group per call
            __builtin_amdgcn_global_load_lds(
                (const __attribute__((address_space(1))) void*)
                    (X + (size_t)(m0 + r0 + srow) * DIMC + k0 + scol),
                (__attribute__((address_space(3))) void*)(As + r0 * 32),
                16, 0, 0);
            __builtin_amdgcn_global_load_lds(
                (const __attribute__((address_space(1))) void*)
                    (W + (size_t)(n0 + r0 + srow) * DIMC + k0 + scol),
                (__attribute__((address_space(3))) void*)(Bs + r0 * 32),
                16, 0, 0);
        }
        __syncthreads();   // vmcnt drain: staged data visible

        bf16x8 af[4], bfr[4];
        #pragma unroll
        for (int i = 0; i < 4; ++i)
            af[i] = *(const bf16x8*)(As + (wm + i * 16 + fr) * 32 + fk);
        #pragma unroll
        for (int j = 0; j < 4; ++j)
            bfr[j] = *(const bf16x8*)(Bs + (wn + j * 16 + fr) * 32 + fk);
        #pragma unroll
        for (int i = 0; i < 4; ++i)
            #pragma unroll
            for (int j = 0; j < 4; ++j)
                acc[i][j] = __builtin_amdgcn_mfma_f32_16x16x32_bf16(
                    af[i], bfr[j], acc[i][j], 0, 0, 0);
    }

    // epilogue: C/D layout col=lane&15, row=(lane>>4)*4+reg
    const int col_l = lane & 15, quad = lane >> 4;
    #pragma unroll
    for (int j = 0; j < 4; ++j) {
        const int gcol = n0 + wn + j * 16 + col_l;
        const float bb = bias[gcol];
        #pragma unroll
        for (int i = 0; i < 4; ++i) {
            #pragma unroll
            for (int r = 0; r < 4; ++r) {
                const int grow = m0 + wm + i * 16 + quad * 4 + r;
                float v = acc[i][j][r] + bb;
                if (do_phi) v = phi_f(v);
                if (OUT_BF16)
                    ((__bf16*)Yv)[(size_t)grow * DIMC + gcol] = (__bf16)v;
                else
                    ((float*)Yv)[(size_t)grow * DIMC + gcol] = v;
            }
        }
    }
}

// ---------------------------------------------------------------------------
// Fused Q/K/V projection, matrix-major XCD ordering: per XCD, sweep one W
// matrix at a time (nb fastest, m middle, mat slowest) so the L2 working set
// is W_mat (2 MB, hot) + a streaming window of X panels. X rereads (3x) are
// absorbed by L3; W is fetched once per XCD per matrix.
// ---------------------------------------------------------------------------
__global__ __launch_bounds__(256, 3) void gemm_qkv(
    const __bf16* __restrict__ X,
    const __bf16* __restrict__ Wq, const __bf16* __restrict__ Wk,
    const __bf16* __restrict__ Wv,
    const float* __restrict__ bq, const float* __restrict__ bk,
    const float* __restrict__ bv,
    __bf16* __restrict__ Q, __bf16* __restrict__ K, __bf16* __restrict__ V)
{
    const int l = blockIdx.x;
    const int xcd = l & 7, s = l >> 3;          // s in [0,384)
    const int mat = s >> 7;                     // 128 blocks per matrix
    const int t = s & 127;
    const int nb = t & 7;                       // fastest: n-block
    const int m_idx = xcd * 16 + (t >> 3);      // middle: 16 m-panels per XCD
    const __bf16* W = (mat == 0) ? Wq : (mat == 1) ? Wk : Wv;
    const float* bias = (mat == 0) ? bq : (mat == 1) ? bk : bv;
    __bf16* Y = (mat == 0) ? Q : (mat == 1) ? K : V;
    gemm_tile<1>(X, W, bias, Y, m_idx * 128, nb * 128, mat != 2);
}

// ---------------------------------------------------------------------------
// Output projection: out = A @ Wo^T + bo (fp32 out). XCD-swizzled; Wo (2 MB)
// stays hot in each XCD's L2.
// ---------------------------------------------------------------------------
__global__ __launch_bounds__(256, 3) void gemm_out(
    const __bf16* __restrict__ A, const __bf16* __restrict__ Wo,
    const float* __restrict__ bo, float* __restrict__ out)
{
    const int l = blockIdx.x;
    const int xcd = l & 7, s = l >> 3;          // s in [0,128)
    const int m_idx = xcd * 16 + (s >> 3);
    const int nb = s & 7;
    gemm_tile<0>(A, Wo, bo, out, m_idx * 128, nb * 128, 0);
}

// ---------------------------------------------------------------------------
// Per (b,h,split): partial KV[d][e] = sum_n K[n,d]*V[n,e], partial Z[d].
// MFMA over LDS-transposed tiles; partials streamed, no global atomics.
// ---------------------------------------------------------------------------
__global__ __launch_bounds__(256) void kv_z_kernel(
    const __bf16* __restrict__ Kb, const __bf16* __restrict__ Vb,
    float* __restrict__ P)
{
    __shared__ __attribute__((aligned(16))) __bf16 Kt[64 * 36]; // [d][tok]
    __shared__ __attribute__((aligned(16))) __bf16 Vt[64 * 36]; // [e][tok]
    __shared__ float zs[64];
    const int tid = threadIdx.x, wave = tid >> 6, lane = tid & 63;
    const int bh = blockIdx.x, b = bh >> 4, h = bh & 15;
    const int split = blockIdx.y;
    const int n0 = split * (SEQ / NSPLIT);
    const int dg = (tid & 15) * 4;     // 4 consecutive dims per thread
    const int u2 = (tid >> 4) * 2;     // token pair
    const int fr = lane & 15, fk = (lane >> 4) * 8;
    const __bf16* Kp = Kb + ((size_t)b * SEQ + n0) * DIMC + h * HD;
    const __bf16* Vp = Vb + ((size_t)b * SEQ + n0) * DIMC + h * HD;

    if (tid < 64) zs[tid] = 0.0f;
    f32x4 acc[4] = {};
    float zp[4] = {};

    for (int c = 0; c < SEQ / NSPLIT; c += 32) {
        bf16x4 ka = *(const bf16x4*)(Kp + (size_t)(c + u2) * DIMC + dg);
        bf16x4 kb = *(const bf16x4*)(Kp + (size_t)(c + u2 + 1) * DIMC + dg);
        bf16x4 va = *(const bf16x4*)(Vp + (size_t)(c + u2) * DIMC + dg);
        bf16x4 vb = *(const bf16x4*)(Vp + (size_t)(c + u2 + 1) * DIMC + dg);
        __syncthreads();
        #pragma unroll
        for (int q = 0; q < 4; ++q) {
            zp[q] += (float)ka[q] + (float)kb[q];
            *(bf16x2*)(Kt + (dg + q) * 36 + u2) = bf16x2{ka[q], kb[q]};
            *(bf16x2*)(Vt + (dg + q) * 36 + u2) = bf16x2{va[q], vb[q]};
        }
        __syncthreads();

        const __bf16* ar = Kt + (wave * 16 + fr) * 36 + fk;
        bf16x4 alo = *(const bf16x4*)ar, ahi = *(const bf16x4*)(ar + 4);
        bf16x8 af = {alo[0],alo[1],alo[2],alo[3],ahi[0],ahi[1],ahi[2],ahi[3]};
        #pragma unroll
        for (int j = 0; j < 4; ++j) {
            const __bf16* br = Vt + (j * 16 + fr) * 36 + fk;
            bf16x4 blo = *(const bf16x4*)br, bhi = *(const bf16x4*)(br + 4);
            bf16x8 bf = {blo[0],blo[1],blo[2],blo[3],bhi[0],bhi[1],bhi[2],bhi[3]};
            acc[j] = __builtin_amdgcn_mfma_f32_16x16x32_bf16(af, bf, acc[j], 0, 0, 0);
        }
    }

    #pragma unroll
    for (int q = 0; q < 4; ++q) atomicAdd(&zs[dg + q], zp[q]);
    __syncthreads();

    float* KVp = P + (size_t)split * PELEMS + bh * 4096;
    const int col_l = lane & 15, quad = lane >> 4;
    #pragma unroll
    for (int j = 0; j < 4; ++j)
        #pragma unroll
        for (int r = 0; r < 4; ++r)
            KVp[(wave * 16 + quad * 4 + r) * 64 + j * 16 + col_l] = acc[j][r];
    if (tid < 64)
        P[(size_t)split * PELEMS + 64 * 64 * 64 + bh * 64 + tid] = zs[tid];
}

// sum NSPLIT partials -> final KV+Z (contiguous PELEMS floats)
__global__ __launch_bounds__(256) void reduce_partials(
    const float* __restrict__ P, float* __restrict__ F)
{
    const int i = blockIdx.x * 256 + threadIdx.x;
    if (i < PELEMS) {
        float s = 0.0f;
        #pragma unroll
        for (int sp = 0; sp < NSPLIT; ++sp) s += P[(size_t)sp * PELEMS + i];
        F[i] = s;
    }
}

// ---------------------------------------------------------------------------
// Per (b,h, 32-token chunk): out[n,e] = (sum_d Q[n,d]*KV[d,e]) / (Q[n]·Z + eps)
// ---------------------------------------------------------------------------
__global__ __launch_bounds__(256) void attn_apply(
    const __bf16* __restrict__ Qb, const float* __restrict__ KV,
    const float* __restrict__ Z, __bf16* __restrict__ Ab)
{
    __shared__ __align__(16) float KVs[64][64];
    __shared__ __align__(16) float Qs[32][64];
    __shared__ float Zs[64];
    __shared__ float rnorm[32];
    const int tid = threadIdx.x;
    const int bh = blockIdx.y;
    const int b = bh >> 4, h = bh & 15;
    const int n0 = blockIdx.x * 32;

    const float* KVp = KV + (size_t)bh * HD * HD;
    #pragma unroll
    for (int r = 0; r < 4; ++r) {
        const int idx = (r * 256 + tid) * 4;
        *(float4*)&((float*)KVs)[idx] = *(const float4*)(KVp + idx);
    }
    const __bf16* Qp = Qb + ((size_t)(b * SEQ + n0)) * DIMC + h * HD;
    {
        const int tok = tid >> 3, col = (tid & 7) * 8;
        bf16x8 q8 = *(const bf16x8*)(Qp + (size_t)tok * DIMC + col);
        #pragma unroll
        for (int q = 0; q < 8; ++q) Qs[tok][col + q] = (float)q8[q];
    }
    if (tid < 64) Zs[tid] = Z[bh * HD + tid];
    __syncthreads();

    if (tid < 32) {
        float s = 0.0f;
        #pragma unroll
        for (int d = 0; d < 64; ++d) s += Qs[tid][d] * Zs[d];
        rnorm[tid] = 1.0f / (s + EPS);
    }
    __syncthreads();

    const int trow = tid >> 3;
    const int e0 = (tid & 7) * 8;
    float out[8] = {};
    #pragma unroll
    for (int d = 0; d < 64; ++d) {
        const float q = Qs[trow][d];
        #pragma unroll
        for (int j = 0; j < 8; ++j) out[j] = fmaf(q, KVs[d][e0 + j], out[j]);
    }
    const float rn = rnorm[trow];
    __bf16* Op = Ab + ((size_t)(b * SEQ + n0 + trow)) * DIMC + h * HD + e0;
    bf16x8 o;
    #pragma unroll
    for (int j = 0; j < 8; ++j) o[j] = (__bf16)(out[j] * rn);
    *(bf16x8*)Op = o;
}

extern "C" void kernel_launch(void* const* d_in, const int* in_sizes, int n_in,
                              void* d_out, int out_size, void* d_ws, size_t ws_size,
                              hipStream_t stream) {
    const float* x  = (const float*)d_in[0];
    const float* Wq = (const float*)d_in[1];
    const float* bq = (const float*)d_in[2];
    const float* Wk = (const float*)d_in[3];
    const float* bk = (const float*)d_in[4];
    const float* Wv = (const float*)d_in[5];
    const float* bv = (const float*)d_in[6];
    const float* Wo = (const float*)d_in[7];
    const float* bo = (const float*)d_in[8];
    float* out = (float*)d_out;

    const size_t big = (size_t)MTOT * DIMC;     // 16,777,216 elems
    const size_t wsz = (size_t)DIMC * DIMC;     // 1,048,576 elems
    __bf16* wsp = (__bf16*)d_ws;
    __bf16* xb  = wsp;
    __bf16* Wqb = xb + big;
    __bf16* Wkb = Wqb + wsz;
    __bf16* Wvb = Wkb + wsz;
    __bf16* Wob = Wvb + wsz;
    __bf16* Qb  = Wob + wsz;
    __bf16* Kb  = Qb + big;
    __bf16* Vb  = Kb + big;
    __bf16* Ab  = xb;                            // alias: x dead after QKV
    float*  P   = (float*)(Vb + big);            // NSPLIT * PELEMS partials
    float*  F   = P + (size_t)NSPLIT * PELEMS;
    float*  KV  = F;
    float*  Z   = F + 64 * 64 * 64;

    const size_t ntot = big + 4 * wsz;           // 20,971,520 elems
    cvt_all<<<dim3((int)(ntot / 1024)), 256, 0, stream>>>(
        x, Wq, Wk, Wv, Wo, xb, Wqb, Wkb, Wvb, Wob);

    gemm_qkv<<<dim3(3072), 256, 0, stream>>>(
        xb, Wqb, Wkb, Wvb, bq, bk, bv, Qb, Kb, Vb);

    kv_z_kernel<<<dim3(BATCH * NH, NSPLIT), 256, 0, stream>>>(Kb, Vb, P);
    reduce_partials<<<dim3((PELEMS + 255) / 256), 256, 0, stream>>>(P, F);
    attn_apply<<<dim3(SEQ / 32, BATCH * NH), 256, 0, stream>>>(Qb, KV, Z, Ab);

    gemm_out<<<dim3(1024), 256, 0, stream>>>(Ab, Wob, bo, out);
}